// Round 6
// baseline (1229.761 us; speedup 1.0000x reference)
//
#include <hip/hip_runtime.h>
#include <hip/hip_bf16.h>

typedef __attribute__((ext_vector_type(4))) float f32x4;
typedef __attribute__((ext_vector_type(8))) __bf16 bf16x8;

// ---- helpers ----------------------------------------------------------------

__device__ inline unsigned short f2bf(float f) {
  union { float f; unsigned u; } x; x.f = f;
  unsigned r = x.u + 0x7fffu + ((x.u >> 16) & 1u);   // RNE
  return (unsigned short)(r >> 16);
}

// async global->LDS, 16B per lane, wave-uniform LDS base + lane*16
__device__ inline void gload16(const ushort* g, ushort* l) {
  __builtin_amdgcn_global_load_lds(
      (const __attribute__((address_space(1))) unsigned int*)(const void*)g,
      (__attribute__((address_space(3))) unsigned int*)(void*)l, 16, 0, 0);
}

// Stage 128x64 bf16 tile into linear LDS [128][64], source-swizzled:
// LDS chunk c holds global (m=c>>3, q=(c&7)^(m&7)). Reads apply the same XOR.
__device__ inline void stage64(const ushort* __restrict__ g, int ldg, ushort* l) {
  int tid = threadIdx.x;
#pragma unroll
  for (int t = 0; t < 4; ++t) {
    int c = tid + t * 256;
    int m = c >> 3, q = (c & 7) ^ (m & 7);
    gload16(g + (size_t)m * ldg + q * 8, l + c * 8);
  }
}

// Stage 64x128 bf16 tile into linear LDS [64][128], source-swizzled:
// 16 chunks/row, chunk' = q ^ (row&15).
__device__ inline void stage_k64(const ushort* __restrict__ g, ushort* l) {
  int tid = threadIdx.x;
#pragma unroll
  for (int t = 0; t < 4; ++t) {
    int c = tid + t * 256;
    int m = c >> 4, q = (c & 15) ^ (m & 15);
    gload16(g + (size_t)m * 128 + q * 8, l + c * 8);
  }
}

// One BK=64 step of 128x128 MFMA compute from linear-swizzled [128][64] tiles.
__device__ inline void mma_tile64(const ushort* lA, const ushort* lB, f32x4 acc[4][4]) {
  int lane = threadIdx.x & 63, w = threadIdx.x >> 6;
  int wm = (w & 1) << 6, wn = (w >> 1) << 6;
  int row = lane & 15, quad = lane >> 4;
  int r7 = row & 7;
#pragma unroll
  for (int kk = 0; kk < 64; kk += 32) {
    int sw = (((kk >> 3) + quad) ^ r7) << 3;
    bf16x8 a[4], b[4];
#pragma unroll
    for (int i = 0; i < 4; ++i)
      a[i] = *(const bf16x8*)(lA + (wm + i * 16 + row) * 64 + sw);
#pragma unroll
    for (int j = 0; j < 4; ++j)
      b[j] = *(const bf16x8*)(lB + (wn + j * 16 + row) * 64 + sw);
#pragma unroll
    for (int i = 0; i < 4; ++i)
#pragma unroll
      for (int j = 0; j < 4; ++j)
        acc[i][j] = __builtin_amdgcn_mfma_f32_16x16x32_bf16(a[i], b[j], acc[i][j], 0, 0, 0);
  }
}

// ---- prep kernels -----------------------------------------------------------

__global__ __launch_bounds__(256) void k_cvt_bf16(const float* __restrict__ in,
                                                  ushort* __restrict__ out, int n4) {
  int i = blockIdx.x * 256 + threadIdx.x;
  if (i >= n4) return;
  float4 v = *(const float4*)(in + (size_t)i * 4);
  ushort4 o; o.x = f2bf(v.x); o.y = f2bf(v.y); o.z = f2bf(v.z); o.w = f2bf(v.w);
  *(ushort4*)(out + (size_t)i * 4) = o;
}

// out[c][r] = bf16(in[r][c]); in is [R][C] fp32, out is [C][R] bf16
__global__ __launch_bounds__(256) void k_transpose_bf16(const float* __restrict__ in,
                                                        ushort* __restrict__ out, int R, int C) {
  __shared__ __align__(16) ushort t[64][72];
  int c0 = blockIdx.x << 6, r0 = blockIdx.y << 6;
  int tid = threadIdx.x;
#pragma unroll
  for (int it = 0; it < 4; ++it) {
    int idx = tid + it * 256;
    int r = idx >> 4, c4 = (idx & 15) << 2;
    float4 v = *(const float4*)(in + (size_t)(r0 + r) * C + c0 + c4);
    t[c4][r] = f2bf(v.x); t[c4 + 1][r] = f2bf(v.y);
    t[c4 + 2][r] = f2bf(v.z); t[c4 + 3][r] = f2bf(v.w);
  }
  __syncthreads();
#pragma unroll
  for (int it = 0; it < 4; ++it) {
    int idx = tid + it * 256;
    int c = idx >> 4, r4 = (idx & 15) << 2;
    ushort4 o; o.x = t[c][r4]; o.y = t[c][r4 + 1]; o.z = t[c][r4 + 2]; o.w = t[c][r4 + 3];
    *(ushort4*)(out + (size_t)(c0 + c) * R + r0 + r4) = o;
  }
}

// ---- QKV GEMM: [4096,2048] x [2048,6144] ------------------------------------
__global__ __launch_bounds__(256) void k_qkv(const ushort* __restrict__ A,
                                             const ushort* __restrict__ Bt,
                                             ushort* __restrict__ qh,
                                             ushort* __restrict__ kh,
                                             ushort* __restrict__ vt) {
  __shared__ __align__(16) ushort lA[128 * 64];
  __shared__ __align__(16) ushort lB[128 * 64];
  int rt = blockIdx.x, ct = blockIdx.y;
  f32x4 z = {0.f, 0.f, 0.f, 0.f};
  f32x4 acc[4][4];
#pragma unroll
  for (int i = 0; i < 4; ++i)
#pragma unroll
    for (int j = 0; j < 4; ++j) acc[i][j] = z;
  for (int kt = 0; kt < 2048; kt += 64) {
    __syncthreads();
    stage64(A + (size_t)rt * 128 * 2048 + kt, 2048, lA);
    stage64(Bt + (size_t)ct * 128 * 2048 + kt, 2048, lB);
    __syncthreads();
    mma_tile64(lA, lB, acc);
  }
  int lane = threadIdx.x & 63, w = threadIdx.x >> 6;
  int wm = (w & 1) << 6, wn = (w >> 1) << 6;
  int col = lane & 15, rb = (lane >> 4) << 2;
#pragma unroll
  for (int i = 0; i < 4; ++i)
#pragma unroll
    for (int j = 0; j < 4; ++j)
#pragma unroll
      for (int r = 0; r < 4; ++r) {
        int R = rt * 128 + wm + i * 16 + rb + r;
        int C = ct * 128 + wn + j * 16 + col;
        int b = R >> 11, n = R & 2047;
        int seg = C >> 11, hh = (C >> 7) & 15, d = C & 127;
        int bh = b * 16 + hh;
        float v = acc[i][j][r];
        if (seg == 0)      qh[((size_t)bh * 2048 + n) * 128 + d] = f2bf(v * 0.08838834764831845f);
        else if (seg == 1) kh[((size_t)bh * 2048 + n) * 128 + d] = f2bf(v);
        else               vt[((size_t)bh * 128 + d) * 2048 + n] = f2bf(v);
      }
}

// ---- fused attention: single-pass flash + in-kernel normalize tail ----------
// Grid 1024 = 32 bh x 32 row-tiles -> 4 blocks/CU. Q in regs. Loop writes RAW
// S fp32 to attnw (lower tri). Tail: re-read own S (L2-hot), write
// P = exp(S-m)*inv_l in place, zero upper triangle. No separate fixup kernel.
__global__ __launch_bounds__(256, 4) void k_attn(const ushort* __restrict__ qh,
                                                 const ushort* __restrict__ kh,
                                                 const ushort* __restrict__ vt,
                                                 float* __restrict__ attnw,
                                                 ushort* __restrict__ Ao) {
  __shared__ __align__(16) ushort lK[64 * 128];   // K tile (64 kv x 128 d); reused as lP (64x64)
  __shared__ __align__(16) ushort lV[128 * 64];   // V^T tile (128 d x 64 kv)
  __shared__ float mArr[64], lArr[64], corrArr[64], invA[64], tm0[64], tm1[64];

  // XCD swizzle (1024 % 8 == 0, bijective): 128 consecutive logical ids
  // (4 heads) per XCD -> K/V stays L2-resident.
  int raw = blockIdx.x;
  int id = (raw & 7) * 128 + (raw >> 3);
  int t5 = id & 31, p = t5 >> 1;
  int rt = (t5 & 1) ? p : 31 - p;                 // heavy/light interleave
  int bh = id >> 5;

  int tid = threadIdx.x;
  int lane = tid & 63, w = tid >> 6;
  int wm = (w & 1) << 5, wn = (w >> 1) << 5;      // QK quadrants (32x32 per wave)
  int wpv = w << 5;                               // PV col strip (64x32 per wave)
  int c16 = lane & 15, quad = lane >> 4;

  const ushort* Qb = qh + ((size_t)bh * 2048 + rt * 64) * 128;
  const ushort* Kb = kh + (size_t)bh * 2048 * 128;
  const ushort* Vb = vt + (size_t)bh * 128 * 2048;
  float* Pg = attnw + (size_t)bh * 2048 * 2048 + (size_t)(rt * 64) * 2048;

  // Q fragments in registers (32 VGPRs), loaded once
  bf16x8 q[2][4];
#pragma unroll
  for (int i = 0; i < 2; ++i)
#pragma unroll
    for (int ks = 0; ks < 4; ++ks)
      q[i][ks] = *(const bf16x8*)(Qb + (size_t)(wm + i * 16 + c16) * 128 + ks * 32 + quad * 8);

  if (tid < 64) { mArr[tid] = -INFINITY; lArr[tid] = 0.f; }

  f32x4 z = {0.f, 0.f, 0.f, 0.f};
  f32x4 o2[4][2];
#pragma unroll
  for (int i = 0; i < 4; ++i)
#pragma unroll
    for (int j = 0; j < 2; ++j) o2[i][j] = z;
  float* tmw = (wn == 0) ? tm0 : tm1;

  for (int ct = 0; ct <= rt; ++ct) {
    __syncthreads();                               // (a) prev PV done; lK,lV free
    stage_k64(Kb + (size_t)ct * 64 * 128, lK);
    __syncthreads();                               // (b) K ready
    stage64(Vb + ct * 64, 2048, lV);               // async; drains at (e)

    // ---- QK^T (Q regs x K LDS): 32x32 per wave ----
    f32x4 acc[2][2];
#pragma unroll
    for (int i = 0; i < 2; ++i)
#pragma unroll
      for (int j = 0; j < 2; ++j) acc[i][j] = z;
    __builtin_amdgcn_s_setprio(1);
#pragma unroll
    for (int ks = 0; ks < 4; ++ks) {
      int sw = (((ks << 2) + quad) ^ c16) << 3;    // 16 chunks/row XOR row&15 (=c16)
      bf16x8 b[2];
#pragma unroll
      for (int j = 0; j < 2; ++j)
        b[j] = *(const bf16x8*)(lK + (wn + j * 16 + c16) * 128 + sw);
#pragma unroll
      for (int i = 0; i < 2; ++i)
#pragma unroll
        for (int j = 0; j < 2; ++j)
          acc[i][j] = __builtin_amdgcn_mfma_f32_16x16x32_bf16(q[i][ks], b[j], acc[i][j], 0, 0, 0);
    }
    __builtin_amdgcn_s_setprio(0);

    bool diag = (ct == rt);
    // ---- per-row tile max ----
#pragma unroll
    for (int i = 0; i < 2; ++i)
#pragma unroll
      for (int r = 0; r < 4; ++r) {
        int lr = wm + i * 16 + quad * 4 + r;
        float mx = -INFINITY;
#pragma unroll
        for (int j = 0; j < 2; ++j) {
          int lc = wn + j * 16 + c16;
          if (!diag || lc <= lr) mx = fmaxf(mx, acc[i][j][r]);
        }
#pragma unroll
        for (int o = 1; o < 16; o <<= 1) mx = fmaxf(mx, __shfl_xor(mx, o));
        if (c16 == 0) tmw[lr] = mx;
      }
    __syncthreads();                               // (e) tm ready; V drained
    if (tid < 64) {
      float tmax = fmaxf(tm0[tid], tm1[tid]);
      float mo = mArr[tid];
      float mn = fmaxf(mo, tmax);
      float corr = (mo == -INFINITY) ? 0.f : __expf(mo - mn);
      mArr[tid] = mn; corrArr[tid] = corr; lArr[tid] *= corr;
    }
    __syncthreads();                               // (f2) m/corr published

    // ---- e=exp(S-m), raw S->global, P->LDS (swizzled), row sums ----
#pragma unroll
    for (int i = 0; i < 2; ++i)
#pragma unroll
      for (int r = 0; r < 4; ++r) {
        int lr = wm + i * 16 + quad * 4 + r;
        float mn = mArr[lr];
        float s = 0.f;
        float* prow = Pg + (size_t)lr * 2048 + ct * 64;
#pragma unroll
        for (int j = 0; j < 2; ++j) {
          int lc = wn + j * 16 + c16;
          float sv = acc[i][j][r];
          prow[lc] = sv;                           // raw S; tail masks/normalizes
          float e = (!diag || lc <= lr) ? __expf(sv - mn) : 0.f;
          s += e;
          lK[lr * 64 + ((((lc >> 3) ^ (lr & 7)) << 3) | (lc & 7))] = f2bf(e);
        }
#pragma unroll
        for (int o = 1; o < 16; o <<= 1) s += __shfl_xor(s, o);
        if (c16 == 0) tmw[lr] = s;
      }
    // ---- O rescale (corrArr stable since f2) ----
#pragma unroll
    for (int i = 0; i < 4; ++i)
#pragma unroll
      for (int r = 0; r < 4; ++r) {
        float cr = corrArr[i * 16 + quad * 4 + r];
#pragma unroll
        for (int j = 0; j < 2; ++j) o2[i][j][r] *= cr;
      }
    __syncthreads();                               // (g2) lP + sums ready
    if (tid < 64) lArr[tid] += tm0[tid] + tm1[tid];

    // ---- PV (P LDS x V LDS): 64 rows x 32 cols per wave ----
    __builtin_amdgcn_s_setprio(1);
#pragma unroll
    for (int ks = 0; ks < 2; ++ks) {
      int swp = (((ks << 2) + quad) ^ (c16 & 7)) << 3;  // 8 chunks/row XOR row&7
      bf16x8 a[4], b[2];
#pragma unroll
      for (int i = 0; i < 4; ++i)
        a[i] = *(const bf16x8*)(lK + (i * 16 + c16) * 64 + swp);
#pragma unroll
      for (int j = 0; j < 2; ++j)
        b[j] = *(const bf16x8*)(lV + (wpv + j * 16 + c16) * 64 + swp);
#pragma unroll
      for (int i = 0; i < 4; ++i)
#pragma unroll
        for (int j = 0; j < 2; ++j)
          o2[i][j] = __builtin_amdgcn_mfma_f32_16x16x32_bf16(a[i], b[j], o2[i][j], 0, 0, 0);
    }
    __builtin_amdgcn_s_setprio(0);
  }

  // ---- epilogue: O scaled by 1/l ----
  if (tid < 64) invA[tid] = 1.f / lArr[tid];
  __syncthreads();
  int b_ = bh >> 4, hh = bh & 15;
#pragma unroll
  for (int i = 0; i < 4; ++i)
#pragma unroll
    for (int j = 0; j < 2; ++j)
#pragma unroll
      for (int r = 0; r < 4; ++r) {
        int row = i * 16 + quad * 4 + r;
        int col = wpv + j * 16 + c16;
        Ao[((size_t)b_ * 2048 + rt * 64 + row) * 2048 + hh * 128 + col] =
            f2bf(o2[i][j][r] * invA[row]);
      }

  // ---- tail: in-place normalize S -> P, zero upper triangle ----
  // 64 rows x 2048 cols fp32 = 512 KB, fully coalesced float4; S region is
  // this block's own recent writes (L2-hot). m/inv are wave-uniform per iter.
  for (int it = 0; it < 128; ++it) {
    int idx = tid + it * 256;
    int r = idx >> 9;                  // row 0..63 (uniform within an iter)
    int c0 = (idx & 511) << 2;         // col 0..2044
    int n = rt * 64 + r;               // global row = causal bound
    float m = mArr[r], inv = invA[r];
    float* row = Pg + (size_t)r * 2048;
    float4 o;
    if (c0 + 3 <= n) {
      float4 s = *(const float4*)(row + c0);
      o.x = __expf(s.x - m) * inv; o.y = __expf(s.y - m) * inv;
      o.z = __expf(s.z - m) * inv; o.w = __expf(s.w - m) * inv;
    } else if (c0 > n) {
      o = make_float4(0.f, 0.f, 0.f, 0.f);
    } else {
      float4 s = *(const float4*)(row + c0);
      o.x = (c0     <= n) ? __expf(s.x - m) * inv : 0.f;
      o.y = (c0 + 1 <= n) ? __expf(s.y - m) * inv : 0.f;
      o.z = (c0 + 2 <= n) ? __expf(s.z - m) * inv : 0.f;
      o.w = (c0 + 3 <= n) ? __expf(s.w - m) * inv : 0.f;
    }
    *(float4*)(row + c0) = o;
  }
}

// ---- out = Ao @ w_proj + b_proj --------------------------------------------
__global__ __launch_bounds__(256) void k_proj(const ushort* __restrict__ Ao,
                                              const ushort* __restrict__ Wt,
                                              const float* __restrict__ bias,
                                              float* __restrict__ out) {
  int rt = blockIdx.x, ct = blockIdx.y;
  __shared__ __align__(16) ushort lA[128 * 64];
  __shared__ __align__(16) ushort lB[128 * 64];
  f32x4 z = {0.f, 0.f, 0.f, 0.f};
  f32x4 acc[4][4];
#pragma unroll
  for (int i = 0; i < 4; ++i)
#pragma unroll
    for (int j = 0; j < 4; ++j) acc[i][j] = z;
  for (int kt = 0; kt < 2048; kt += 64) {
    __syncthreads();
    stage64(Ao + (size_t)rt * 128 * 2048 + kt, 2048, lA);
    stage64(Wt + (size_t)ct * 128 * 2048 + kt, 2048, lB);
    __syncthreads();
    mma_tile64(lA, lB, acc);
  }
  int lane = threadIdx.x & 63, w = threadIdx.x >> 6;
  int wm = (w & 1) << 6, wn = (w >> 1) << 6;
  int col = lane & 15, rb = (lane >> 4) << 2;
#pragma unroll
  for (int i = 0; i < 4; ++i)
#pragma unroll
    for (int j = 0; j < 4; ++j)
#pragma unroll
      for (int r = 0; r < 4; ++r) {
        int R = rt * 128 + wm + i * 16 + rb + r;
        int C = ct * 128 + wn + j * 16 + col;
        out[(size_t)R * 2048 + C] = acc[i][j][r] + bias[C];
      }
}

// ---- launch -----------------------------------------------------------------

extern "C" void kernel_launch(void* const* d_in, const int* in_sizes, int n_in,
                              void* d_out, int out_size, void* d_ws, size_t ws_size,
                              hipStream_t stream) {
  const float* hs = (const float*)d_in[0];   // [2,2048,2048]
  const float* wf = (const float*)d_in[1];   // [2048,6144]
  const float* wp = (const float*)d_in[2];   // [2048,2048]
  const float* bp = (const float*)d_in[3];   // [2048]
  float* out = (float*)d_out;                // [2,2048,2048]
  float* attnw = out + (size_t)8388608;      // [2,16,2048,2048]

  ushort* Hb  = (ushort*)d_ws;               // 4096x2048 bf16
  ushort* Wft = Hb  + (size_t)8388608;       // 6144x2048 bf16 (w_fused^T)
  ushort* Wpt = Wft + (size_t)12582912;      // 2048x2048 bf16 (w_proj^T)
  ushort* qh  = Wpt + (size_t)4194304;       // [32][2048][128] bf16, pre-scaled
  ushort* kh  = qh  + (size_t)8388608;       // [32][2048][128] bf16
  ushort* vt  = kh  + (size_t)8388608;       // [32][128][2048] bf16 (V^T)
  ushort* Ao  = vt  + (size_t)8388608;       // [4096][2048] bf16

  k_cvt_bf16<<<8192, 256, 0, stream>>>(hs, Hb, 2097152);
  k_transpose_bf16<<<dim3(96, 32), 256, 0, stream>>>(wf, Wft, 2048, 6144);
  k_transpose_bf16<<<dim3(32, 32), 256, 0, stream>>>(wp, Wpt, 2048, 2048);
  k_qkv<<<dim3(32, 48), 256, 0, stream>>>(Hb, Wft, qh, kh, vt);
  k_attn<<<1024, 256, 0, stream>>>(qh, kh, vt, attnw, Ao);
  k_proj<<<dim3(32, 16), 256, 0, stream>>>(Ao, Wpt, bp, out);
}

// Round 7
// 1068.118 us; speedup vs baseline: 1.1513x; 1.1513x over previous
//
#include <hip/hip_runtime.h>
#include <hip/hip_bf16.h>

typedef __attribute__((ext_vector_type(4))) float f32x4;
typedef __attribute__((ext_vector_type(8))) __bf16 bf16x8;

// ---- helpers ----------------------------------------------------------------

__device__ inline unsigned short f2bf(float f) {
  union { float f; unsigned u; } x; x.f = f;
  unsigned r = x.u + 0x7fffu + ((x.u >> 16) & 1u);   // RNE
  return (unsigned short)(r >> 16);
}

// async global->LDS, 16B per lane, wave-uniform LDS base + lane*16
__device__ inline void gload16(const ushort* g, ushort* l) {
  __builtin_amdgcn_global_load_lds(
      (const __attribute__((address_space(1))) unsigned int*)(const void*)g,
      (__attribute__((address_space(3))) unsigned int*)(void*)l, 16, 0, 0);
}

// Stage 128x64 bf16 tile into linear LDS [128][64], source-swizzled:
// LDS chunk c holds global (m=c>>3, q=(c&7)^(m&7)). Reads apply the same XOR.
__device__ inline void stage64(const ushort* __restrict__ g, int ldg, ushort* l) {
  int tid = threadIdx.x;
#pragma unroll
  for (int t = 0; t < 4; ++t) {
    int c = tid + t * 256;
    int m = c >> 3, q = (c & 7) ^ (m & 7);
    gload16(g + (size_t)m * ldg + q * 8, l + c * 8);
  }
}

// Stage 64x128 bf16 tile into linear LDS [64][128], source-swizzled:
// 16 chunks/row, chunk' = q ^ (row&15).
__device__ inline void stage_k64(const ushort* __restrict__ g, ushort* l) {
  int tid = threadIdx.x;
#pragma unroll
  for (int t = 0; t < 4; ++t) {
    int c = tid + t * 256;
    int m = c >> 4, q = (c & 15) ^ (m & 15);
    gload16(g + (size_t)m * 128 + q * 8, l + c * 8);
  }
}

// One BK=64 step of 128x128 MFMA compute from linear-swizzled [128][64] tiles.
__device__ inline void mma_tile64(const ushort* lA, const ushort* lB, f32x4 acc[4][4]) {
  int lane = threadIdx.x & 63, w = threadIdx.x >> 6;
  int wm = (w & 1) << 6, wn = (w >> 1) << 6;
  int row = lane & 15, quad = lane >> 4;
  int r7 = row & 7;
#pragma unroll
  for (int kk = 0; kk < 64; kk += 32) {
    int sw = (((kk >> 3) + quad) ^ r7) << 3;
    bf16x8 a[4], b[4];
#pragma unroll
    for (int i = 0; i < 4; ++i)
      a[i] = *(const bf16x8*)(lA + (wm + i * 16 + row) * 64 + sw);
#pragma unroll
    for (int j = 0; j < 4; ++j)
      b[j] = *(const bf16x8*)(lB + (wn + j * 16 + row) * 64 + sw);
#pragma unroll
    for (int i = 0; i < 4; ++i)
#pragma unroll
      for (int j = 0; j < 4; ++j)
        acc[i][j] = __builtin_amdgcn_mfma_f32_16x16x32_bf16(a[i], b[j], acc[i][j], 0, 0, 0);
  }
}

// ---- prep kernels -----------------------------------------------------------

__global__ __launch_bounds__(256) void k_cvt_bf16(const float* __restrict__ in,
                                                  ushort* __restrict__ out, int n4) {
  int i = blockIdx.x * 256 + threadIdx.x;
  if (i >= n4) return;
  float4 v = *(const float4*)(in + (size_t)i * 4);
  ushort4 o; o.x = f2bf(v.x); o.y = f2bf(v.y); o.z = f2bf(v.z); o.w = f2bf(v.w);
  *(ushort4*)(out + (size_t)i * 4) = o;
}

// out[c][r] = bf16(in[r][c]); in is [R][C] fp32, out is [C][R] bf16
__global__ __launch_bounds__(256) void k_transpose_bf16(const float* __restrict__ in,
                                                        ushort* __restrict__ out, int R, int C) {
  __shared__ __align__(16) ushort t[64][72];
  int c0 = blockIdx.x << 6, r0 = blockIdx.y << 6;
  int tid = threadIdx.x;
#pragma unroll
  for (int it = 0; it < 4; ++it) {
    int idx = tid + it * 256;
    int r = idx >> 4, c4 = (idx & 15) << 2;
    float4 v = *(const float4*)(in + (size_t)(r0 + r) * C + c0 + c4);
    t[c4][r] = f2bf(v.x); t[c4 + 1][r] = f2bf(v.y);
    t[c4 + 2][r] = f2bf(v.z); t[c4 + 3][r] = f2bf(v.w);
  }
  __syncthreads();
#pragma unroll
  for (int it = 0; it < 4; ++it) {
    int idx = tid + it * 256;
    int c = idx >> 4, r4 = (idx & 15) << 2;
    ushort4 o; o.x = t[c][r4]; o.y = t[c][r4 + 1]; o.z = t[c][r4 + 2]; o.w = t[c][r4 + 3];
    *(ushort4*)(out + (size_t)(c0 + c) * R + r0 + r4) = o;
  }
}

// ---- QKV GEMM: [4096,2048] x [2048,6144] ------------------------------------
__global__ __launch_bounds__(256) void k_qkv(const ushort* __restrict__ A,
                                             const ushort* __restrict__ Bt,
                                             ushort* __restrict__ qh,
                                             ushort* __restrict__ kh,
                                             ushort* __restrict__ vt) {
  __shared__ __align__(16) ushort lA[128 * 64];
  __shared__ __align__(16) ushort lB[128 * 64];
  int rt = blockIdx.x, ct = blockIdx.y;
  f32x4 z = {0.f, 0.f, 0.f, 0.f};
  f32x4 acc[4][4];
#pragma unroll
  for (int i = 0; i < 4; ++i)
#pragma unroll
    for (int j = 0; j < 4; ++j) acc[i][j] = z;
  for (int kt = 0; kt < 2048; kt += 64) {
    __syncthreads();
    stage64(A + (size_t)rt * 128 * 2048 + kt, 2048, lA);
    stage64(Bt + (size_t)ct * 128 * 2048 + kt, 2048, lB);
    __syncthreads();
    mma_tile64(lA, lB, acc);
  }
  int lane = threadIdx.x & 63, w = threadIdx.x >> 6;
  int wm = (w & 1) << 6, wn = (w >> 1) << 6;
  int col = lane & 15, rb = (lane >> 4) << 2;
#pragma unroll
  for (int i = 0; i < 4; ++i)
#pragma unroll
    for (int j = 0; j < 4; ++j)
#pragma unroll
      for (int r = 0; r < 4; ++r) {
        int R = rt * 128 + wm + i * 16 + rb + r;
        int C = ct * 128 + wn + j * 16 + col;
        int b = R >> 11, n = R & 2047;
        int seg = C >> 11, hh = (C >> 7) & 15, d = C & 127;
        int bh = b * 16 + hh;
        float v = acc[i][j][r];
        if (seg == 0)      qh[((size_t)bh * 2048 + n) * 128 + d] = f2bf(v * 0.08838834764831845f);
        else if (seg == 1) kh[((size_t)bh * 2048 + n) * 128 + d] = f2bf(v);
        else               vt[((size_t)bh * 128 + d) * 2048 + n] = f2bf(v);
      }
}

// ---- fused attention: single-pass flash, wave-row-ownership -----------------
// Wave w owns rows [w*16, w*16+16) of the 64-row Q tile for QK^T, softmax AND
// PV. All row stats (m, l, corr, 1/l) live in registers; P strip in lP is
// written and read by the same wave (no barrier). Only cross-wave coupling is
// cooperative K/V staging -> 2 barriers/iter. Raw S fp32 -> attnw (lower tri);
// k_fixup normalizes + zero-fills. LDS = 16+16+8 = 40 KB -> 4 blocks/CU.
__global__ __launch_bounds__(256, 4) void k_attn(const ushort* __restrict__ qh,
                                                 const ushort* __restrict__ kh,
                                                 const ushort* __restrict__ vt,
                                                 float* __restrict__ attnw,
                                                 ushort* __restrict__ Ao,
                                                 float* __restrict__ mf,
                                                 float* __restrict__ il) {
  __shared__ __align__(16) ushort lK[64 * 128];   // K tile (64 kv x 128 d)
  __shared__ __align__(16) ushort lV[128 * 64];   // V^T tile (128 d x 64 kv)
  __shared__ __align__(16) ushort lP[64 * 64];    // P tile (64 q x 64 kv)

  // XCD swizzle (1024 % 8 == 0, bijective): 128 consecutive logical ids
  // (4 heads) per XCD -> K/V stays L2-resident.
  int raw = blockIdx.x;
  int id = (raw & 7) * 128 + (raw >> 3);
  int t5 = id & 31, p = t5 >> 1;
  int rt = (t5 & 1) ? p : 31 - p;                 // heavy/light interleave
  int bh = id >> 5;

  int tid = threadIdx.x;
  int lane = tid & 63, w = tid >> 6;
  int c16 = lane & 15, quad = lane >> 4;
  int wr = w << 4;                                // wave's row base (0,16,32,48)

  const ushort* Qb = qh + ((size_t)bh * 2048 + rt * 64) * 128;
  const ushort* Kb = kh + (size_t)bh * 2048 * 128;
  const ushort* Vb = vt + (size_t)bh * 128 * 2048;
  float* Pg = attnw + (size_t)bh * 2048 * 2048 + (size_t)(rt * 64) * 2048;

  // Q fragments in registers (16 VGPRs), loaded once: rows wr + c16
  bf16x8 q[4];
#pragma unroll
  for (int ks = 0; ks < 4; ++ks)
    q[ks] = *(const bf16x8*)(Qb + (size_t)(wr + c16) * 128 + ks * 32 + quad * 8);

  // per-lane row stats (rows wr + quad*4 + r, replicated across c16 group)
  float m_[4], l_[4];
#pragma unroll
  for (int r = 0; r < 4; ++r) { m_[r] = -INFINITY; l_[r] = 0.f; }

  f32x4 z = {0.f, 0.f, 0.f, 0.f};
  f32x4 o2[8];                                    // O rows (own 16) x 128 cols
#pragma unroll
  for (int j = 0; j < 8; ++j) o2[j] = z;

  for (int ct = 0; ct <= rt; ++ct) {
    __syncthreads();                               // (a) prev QK/PV reads done
    stage_k64(Kb + (size_t)ct * 64 * 128, lK);
    stage64(Vb + ct * 64, 2048, lV);
    __syncthreads();                               // (b) K,V staged (drain)

    // ---- QK^T: own 16 rows x 64 cols ----
    f32x4 acc[4];
#pragma unroll
    for (int j = 0; j < 4; ++j) acc[j] = z;
    __builtin_amdgcn_s_setprio(1);
#pragma unroll
    for (int ks = 0; ks < 4; ++ks) {
      int sw = (((ks << 2) + quad) ^ c16) << 3;    // chunk XOR row&15 (=c16)
      bf16x8 b[4];
#pragma unroll
      for (int j = 0; j < 4; ++j)
        b[j] = *(const bf16x8*)(lK + (j * 16 + c16) * 128 + sw);
#pragma unroll
      for (int j = 0; j < 4; ++j)
        acc[j] = __builtin_amdgcn_mfma_f32_16x16x32_bf16(q[ks], b[j], acc[j], 0, 0, 0);
    }
    __builtin_amdgcn_s_setprio(0);

    bool diag = (ct == rt);
    // ---- softmax: all stats in registers, butterfly over c16 group ----
#pragma unroll
    for (int r = 0; r < 4; ++r) {
      int lr = wr + quad * 4 + r;                  // local row 0..63
      float mx = -INFINITY;
#pragma unroll
      for (int j = 0; j < 4; ++j) {
        int lc = j * 16 + c16;
        if (!diag || lc <= lr) mx = fmaxf(mx, acc[j][r]);
      }
#pragma unroll
      for (int o = 1; o < 16; o <<= 1) mx = fmaxf(mx, __shfl_xor(mx, o));
      float mn = fmaxf(m_[r], mx);
      float corr = (m_[r] == -INFINITY) ? 0.f : __expf(m_[r] - mn);
      float s = 0.f;
      float* prow = Pg + (size_t)lr * 2048 + ct * 64;
#pragma unroll
      for (int j = 0; j < 4; ++j) {
        int lc = j * 16 + c16;
        float sv = acc[j][r];
        prow[lc] = sv;                             // raw S; fixup masks/normalizes
        float e = (!diag || lc <= lr) ? __expf(sv - mn) : 0.f;
        s += e;
        lP[lr * 64 + ((((lc >> 3) ^ (lr & 7)) << 3) | (lc & 7))] = f2bf(e);
      }
#pragma unroll
      for (int o = 1; o < 16; o <<= 1) s += __shfl_xor(s, o);
      m_[r] = mn;
      l_[r] = l_[r] * corr + s;
#pragma unroll
      for (int j = 0; j < 8; ++j) o2[j][r] *= corr;
    }

    // ---- PV: A = own P rows (wave-local, no barrier), B = V ----
    __builtin_amdgcn_s_setprio(1);
#pragma unroll
    for (int ks = 0; ks < 2; ++ks) {
      int swp = (((ks << 2) + quad) ^ (c16 & 7)) << 3;  // chunk XOR row&7
      bf16x8 a = *(const bf16x8*)(lP + (wr + c16) * 64 + swp);
      bf16x8 b[8];
#pragma unroll
      for (int j = 0; j < 8; ++j)
        b[j] = *(const bf16x8*)(lV + (j * 16 + c16) * 64 + swp);
#pragma unroll
      for (int j = 0; j < 8; ++j)
        o2[j] = __builtin_amdgcn_mfma_f32_16x16x32_bf16(a, b[j], o2[j], 0, 0, 0);
    }
    __builtin_amdgcn_s_setprio(0);
  }

  // ---- epilogue: stats to global, O scaled by 1/l (all regs) ----
  float inv_[4];
#pragma unroll
  for (int r = 0; r < 4; ++r) inv_[r] = 1.f / l_[r];
  if (c16 == 0) {
#pragma unroll
    for (int r = 0; r < 4; ++r) {
      int g = bh * 2048 + rt * 64 + wr + quad * 4 + r;
      mf[g] = m_[r]; il[g] = inv_[r];
    }
  }
  int b_ = bh >> 4, hh = bh & 15;
#pragma unroll
  for (int j = 0; j < 8; ++j)
#pragma unroll
    for (int r = 0; r < 4; ++r) {
      int row = wr + quad * 4 + r;
      int col = j * 16 + c16;
      Ao[((size_t)b_ * 2048 + rt * 64 + row) * 2048 + hh * 128 + col] =
          f2bf(o2[j][r] * inv_[r]);
    }
}

// ---- streaming normalize: S -> exp(S-m)*inv_l, zero upper triangle ----------
__global__ __launch_bounds__(256) void k_fixup(float* __restrict__ attnw,
                                               const float* __restrict__ mf,
                                               const float* __restrict__ il) {
  int n = blockIdx.x, bh = blockIdx.y;
  float m = mf[bh * 2048 + n];
  float inv = il[bh * 2048 + n];
  float* row = attnw + ((size_t)bh * 2048 + n) * 2048;
  int tid = threadIdx.x;
#pragma unroll
  for (int t = 0; t < 2; ++t) {
    int c0 = (tid + t * 256) << 2;
    float4 o;
    if (c0 + 3 <= n) {
      float4 s = *(const float4*)(row + c0);
      o.x = __expf(s.x - m) * inv; o.y = __expf(s.y - m) * inv;
      o.z = __expf(s.z - m) * inv; o.w = __expf(s.w - m) * inv;
    } else if (c0 > n) {
      o = make_float4(0.f, 0.f, 0.f, 0.f);
    } else {
      float4 s = *(const float4*)(row + c0);
      o.x = (c0     <= n) ? __expf(s.x - m) * inv : 0.f;
      o.y = (c0 + 1 <= n) ? __expf(s.y - m) * inv : 0.f;
      o.z = (c0 + 2 <= n) ? __expf(s.z - m) * inv : 0.f;
      o.w = (c0 + 3 <= n) ? __expf(s.w - m) * inv : 0.f;
    }
    *(float4*)(row + c0) = o;
  }
}

// ---- out = Ao @ w_proj + b_proj --------------------------------------------
__global__ __launch_bounds__(256) void k_proj(const ushort* __restrict__ Ao,
                                              const ushort* __restrict__ Wt,
                                              const float* __restrict__ bias,
                                              float* __restrict__ out) {
  int rt = blockIdx.x, ct = blockIdx.y;
  __shared__ __align__(16) ushort lA[128 * 64];
  __shared__ __align__(16) ushort lB[128 * 64];
  f32x4 z = {0.f, 0.f, 0.f, 0.f};
  f32x4 acc[4][4];
#pragma unroll
  for (int i = 0; i < 4; ++i)
#pragma unroll
    for (int j = 0; j < 4; ++j) acc[i][j] = z;
  for (int kt = 0; kt < 2048; kt += 64) {
    __syncthreads();
    stage64(Ao + (size_t)rt * 128 * 2048 + kt, 2048, lA);
    stage64(Wt + (size_t)ct * 128 * 2048 + kt, 2048, lB);
    __syncthreads();
    mma_tile64(lA, lB, acc);
  }
  int lane = threadIdx.x & 63, w = threadIdx.x >> 6;
  int wm = (w & 1) << 6, wn = (w >> 1) << 6;
  int col = lane & 15, rb = (lane >> 4) << 2;
#pragma unroll
  for (int i = 0; i < 4; ++i)
#pragma unroll
    for (int j = 0; j < 4; ++j)
#pragma unroll
      for (int r = 0; r < 4; ++r) {
        int R = rt * 128 + wm + i * 16 + rb + r;
        int C = ct * 128 + wn + j * 16 + col;
        out[(size_t)R * 2048 + C] = acc[i][j][r] + bias[C];
      }
}

// ---- launch -----------------------------------------------------------------

extern "C" void kernel_launch(void* const* d_in, const int* in_sizes, int n_in,
                              void* d_out, int out_size, void* d_ws, size_t ws_size,
                              hipStream_t stream) {
  const float* hs = (const float*)d_in[0];   // [2,2048,2048]
  const float* wf = (const float*)d_in[1];   // [2048,6144]
  const float* wp = (const float*)d_in[2];   // [2048,2048]
  const float* bp = (const float*)d_in[3];   // [2048]
  float* out = (float*)d_out;                // [2,2048,2048]
  float* attnw = out + (size_t)8388608;      // [2,16,2048,2048]

  ushort* Hb  = (ushort*)d_ws;               // 4096x2048 bf16
  ushort* Wft = Hb  + (size_t)8388608;       // 6144x2048 bf16 (w_fused^T)
  ushort* Wpt = Wft + (size_t)12582912;      // 2048x2048 bf16 (w_proj^T)
  ushort* qh  = Wpt + (size_t)4194304;       // [32][2048][128] bf16, pre-scaled
  ushort* kh  = qh  + (size_t)8388608;       // [32][2048][128] bf16
  ushort* vt  = kh  + (size_t)8388608;       // [32][128][2048] bf16 (V^T)
  ushort* Ao  = vt  + (size_t)8388608;       // [4096][2048] bf16
  // stats live in the Hb region (free after k_qkv): 2 x 64K floats = 512 KB
  float* mf = (float*)Hb;
  float* il = mf + 65536;

  k_cvt_bf16<<<8192, 256, 0, stream>>>(hs, Hb, 2097152);
  k_transpose_bf16<<<dim3(96, 32), 256, 0, stream>>>(wf, Wft, 2048, 6144);
  k_transpose_bf16<<<dim3(32, 32), 256, 0, stream>>>(wp, Wpt, 2048, 2048);
  k_qkv<<<dim3(32, 48), 256, 0, stream>>>(Hb, Wft, qh, kh, vt);
  k_attn<<<1024, 256, 0, stream>>>(qh, kh, vt, attnw, Ao, mf, il);
  k_fixup<<<dim3(2048, 32), 256, 0, stream>>>(attnw, mf, il);
  k_proj<<<dim3(32, 16), 256, 0, stream>>>(Ao, Wpt, bp, out);
}